// Round 1
// 274.608 us; speedup vs baseline: 1.0937x; 1.0937x over previous
//
#include <hip/hip_runtime.h>
#include <hip/hip_bf16.h>

// Problem dims (compile-time)
#define SDIM 512   // SEQDIM
#define EDIM 512   // EMBED_DIM
#define LDIM 384   // VFEAT_LEN
#define DDIM 384   // VFEAT_DIM

typedef __attribute__((ext_vector_type(4))) float float4v;

// ---------------------------------------------------------------------------
// Kernel 1: t[e][l] = tanh( sum_k wv[e][k]*v[k][l] + gh[e] ),  gh = wg @ h
// One block per e-row, 384 threads (thread = column). 512 blocks -> 2 blocks/CU,
// 3 waves/SIMD (vs 1 before): latency-bound L2 loads now have TLP to hide under.
// 4 accumulators give 4 independent FMA/load chains per thread.
// ---------------------------------------------------------------------------
__global__ __launch_bounds__(384) void k_tanh_s(
    const float* __restrict__ h, const float* __restrict__ v,
    const float* __restrict__ wv, const float* __restrict__ wg,
    float* __restrict__ t)
{
    const int e   = blockIdx.x;
    const int tid = threadIdx.x;            // 0..383
    __shared__ float wvs[DDIM];             // this wv row
    __shared__ float red[6];                // per-wave partial gh

    // gh[e] = dot(wg[e,:], h) across all 384 threads
    float acc = 0.f;
    for (int k = tid; k < SDIM; k += 384)
        acc += wg[e * SDIM + k] * h[k];
    for (int off = 32; off > 0; off >>= 1)
        acc += __shfl_down(acc, off, 64);
    if ((tid & 63) == 0) red[tid >> 6] = acc;

    // stage wv row in LDS (one element per thread)
    wvs[tid] = wv[e * DDIM + tid];
    __syncthreads();

    const float gh = red[0] + red[1] + red[2] + red[3] + red[4] + red[5];

    // thread tid owns column l = tid
    const float* vp = v + tid;
    float a0 = 0.f, a1 = 0.f, a2 = 0.f, a3 = 0.f;
    #pragma unroll 4
    for (int k = 0; k < DDIM; k += 4) {
        a0 += wvs[k]     * vp[(k)     * LDIM];
        a1 += wvs[k + 1] * vp[(k + 1) * LDIM];
        a2 += wvs[k + 2] * vp[(k + 2) * LDIM];
        a3 += wvs[k + 3] * vp[(k + 3) * LDIM];
    }
    t[e * LDIM + tid] = tanhf((a0 + a1) + (a2 + a3) + gh);
}

// ---------------------------------------------------------------------------
// Kernel 2: z[r][c] = sum_e wh[r][e] * t[e][c]; alpha[r][:] = softmax(z[r][:])
// One block per r-row, 384 threads (thread = column). z stays in a register;
// softmax uses shfl + tiny LDS reduce only (no zr[] LDS round-trip).
// 384 blocks -> 1.5 blocks/CU vs 0.75 before.
// ---------------------------------------------------------------------------
__global__ __launch_bounds__(384) void k_softmax(
    const float* __restrict__ wh, const float* __restrict__ t,
    float* __restrict__ alpha)
{
    const int r   = blockIdx.x;
    const int tid = threadIdx.x;            // 0..383 = column c
    __shared__ float whs[EDIM];             // this wh row
    __shared__ float redm[6];
    __shared__ float reds[6];

    for (int e = tid; e < EDIM; e += 384)
        whs[e] = wh[r * EDIM + e];
    __syncthreads();

    const float* tp = t + tid;
    float a0 = 0.f, a1 = 0.f, a2 = 0.f, a3 = 0.f;
    #pragma unroll 4
    for (int e = 0; e < EDIM; e += 4) {
        a0 += whs[e]     * tp[(e)     * LDIM];
        a1 += whs[e + 1] * tp[(e + 1) * LDIM];
        a2 += whs[e + 2] * tp[(e + 2) * LDIM];
        a3 += whs[e + 3] * tp[(e + 3) * LDIM];
    }
    const float z = (a0 + a1) + (a2 + a3);

    // block max
    float m = z;
    for (int off = 32; off > 0; off >>= 1)
        m = fmaxf(m, __shfl_down(m, off, 64));
    if ((tid & 63) == 0) redm[tid >> 6] = m;
    __syncthreads();
    m = fmaxf(fmaxf(fmaxf(redm[0], redm[1]), fmaxf(redm[2], redm[3])),
              fmaxf(redm[4], redm[5]));

    const float ez = expf(z - m);

    // block sum
    float s = ez;
    for (int off = 32; off > 0; off >>= 1)
        s += __shfl_down(s, off, 64);
    if ((tid & 63) == 0) reds[tid >> 6] = s;
    __syncthreads();
    const float rs = 1.f / (((reds[0] + reds[1]) + (reds[2] + reds[3]))
                            + (reds[4] + reds[5]));

    alpha[r * LDIM + tid] = ez * rs;
}

// ---------------------------------------------------------------------------
// Kernel 3: out[i][j][k] = v[j][k] * alpha[i][j]   (226.5 MB f32 writes)
// 1536 blocks: 4 per i-slice (6 waves/SIMD vs 3 before — more stores in
// flight for the write stream). Alpha row in LDS; magic-div by 96 per vec4;
// nontemporal float4 stores (streaming output, keep L2 for v reads).
// ---------------------------------------------------------------------------
__global__ __launch_bounds__(256) void k_out(
    const float* __restrict__ v, const float* __restrict__ alpha,
    float* __restrict__ out)
{
    constexpr int VPS = (LDIM * DDIM) / 4;   // 36864 vec4 per i-slice
    constexpr int QTR = VPS / 4;             // 9216 vec4 per block
    const int i = blockIdx.x >> 2;
    const int q = blockIdx.x & 3;

    __shared__ float arow[DDIM];
    for (int j = threadIdx.x; j < DDIM; j += 256)
        arow[j] = alpha[i * DDIM + j];
    __syncthreads();

    const float4v* v4 = (const float4v*)v;
    float4v* o4 = (float4v*)out + (size_t)i * VPS;
    const int base = q * QTR;

    #pragma unroll 4
    for (int it = 0; it < QTR / 256; ++it) {        // 36 iterations
        const int idx = base + it * 256 + (int)threadIdx.x;
        const int j   = idx / 96;                   // 96 vec4 per v row
        const float a = arow[j];
        float4v vv = v4[idx];
        vv *= a;
        __builtin_nontemporal_store(vv, o4 + idx);
    }
}

// ---------------------------------------------------------------------------
extern "C" void kernel_launch(void* const* d_in, const int* in_sizes, int n_in,
                              void* d_out, int out_size, void* d_ws, size_t ws_size,
                              hipStream_t stream)
{
    const float* h  = (const float*)d_in[0];   // (512, 1)   f32
    const float* v  = (const float*)d_in[1];   // (384, 384) f32
    const float* wh = (const float*)d_in[2];   // (384, 512) f32
    const float* wv = (const float*)d_in[3];   // (512, 384) f32
    const float* wg = (const float*)d_in[4];   // (512, 512) f32
    float* out = (float*)d_out;                // (384, 384, 384) f32

    float* t     = (float*)d_ws;               // (512, 384) f32 scratch
    float* alpha = t + EDIM * LDIM;            // (384, 384) f32 scratch

    k_tanh_s <<<EDIM, 384, 0, stream>>>(h, v, wv, wg, t);
    k_softmax<<<LDIM, 384, 0, stream>>>(wh, t, alpha);
    k_out    <<<4 * LDIM, 256, 0, stream>>>(v, alpha, out);
}

// Round 2
// 261.761 us; speedup vs baseline: 1.1474x; 1.0491x over previous
//
#include <hip/hip_runtime.h>
#include <hip/hip_bf16.h>

// Problem dims (compile-time)
#define SDIM 512   // SEQDIM
#define EDIM 512   // EMBED_DIM
#define LDIM 384   // VFEAT_LEN
#define DDIM 384   // VFEAT_DIM

typedef __attribute__((ext_vector_type(4))) float float4v;

// ---------------------------------------------------------------------------
// Kernel 1: t[e][l] = tanh( sum_k wv[e][k]*v[k][l] + gh[e] ),  gh = wg @ h
// One block per e-row, 384 threads (thread = column). 512 blocks -> 2 blocks/CU,
// 3 waves/SIMD: latency-bound L2 loads have TLP to hide under.
// 4 accumulators give 4 independent FMA/load chains per thread.
// ---------------------------------------------------------------------------
__global__ __launch_bounds__(384) void k_tanh_s(
    const float* __restrict__ h, const float* __restrict__ v,
    const float* __restrict__ wv, const float* __restrict__ wg,
    float* __restrict__ t)
{
    const int e   = blockIdx.x;
    const int tid = threadIdx.x;            // 0..383
    __shared__ float wvs[DDIM];             // this wv row
    __shared__ float red[6];                // per-wave partial gh

    // gh[e] = dot(wg[e,:], h) across all 384 threads
    float acc = 0.f;
    for (int k = tid; k < SDIM; k += 384)
        acc += wg[e * SDIM + k] * h[k];
    for (int off = 32; off > 0; off >>= 1)
        acc += __shfl_down(acc, off, 64);
    if ((tid & 63) == 0) red[tid >> 6] = acc;

    // stage wv row in LDS (one element per thread)
    wvs[tid] = wv[e * DDIM + tid];
    __syncthreads();

    const float gh = red[0] + red[1] + red[2] + red[3] + red[4] + red[5];

    // thread tid owns column l = tid
    const float* vp = v + tid;
    float a0 = 0.f, a1 = 0.f, a2 = 0.f, a3 = 0.f;
    #pragma unroll 4
    for (int k = 0; k < DDIM; k += 4) {
        a0 += wvs[k]     * vp[(k)     * LDIM];
        a1 += wvs[k + 1] * vp[(k + 1) * LDIM];
        a2 += wvs[k + 2] * vp[(k + 2) * LDIM];
        a3 += wvs[k + 3] * vp[(k + 3) * LDIM];
    }
    t[e * LDIM + tid] = tanhf((a0 + a1) + (a2 + a3) + gh);
}

// ---------------------------------------------------------------------------
// Kernel 2: z[r][c] = sum_e wh[r][e] * t[e][c]; alpha[r][:] = softmax(z[r][:])
// One block per r-row, 384 threads (thread = column). z stays in a register;
// softmax uses shfl + tiny LDS reduce only.
// ---------------------------------------------------------------------------
__global__ __launch_bounds__(384) void k_softmax(
    const float* __restrict__ wh, const float* __restrict__ t,
    float* __restrict__ alpha)
{
    const int r   = blockIdx.x;
    const int tid = threadIdx.x;            // 0..383 = column c
    __shared__ float whs[EDIM];             // this wh row
    __shared__ float redm[6];
    __shared__ float reds[6];

    for (int e = tid; e < EDIM; e += 384)
        whs[e] = wh[r * EDIM + e];
    __syncthreads();

    const float* tp = t + tid;
    float a0 = 0.f, a1 = 0.f, a2 = 0.f, a3 = 0.f;
    #pragma unroll 4
    for (int e = 0; e < EDIM; e += 4) {
        a0 += whs[e]     * tp[(e)     * LDIM];
        a1 += whs[e + 1] * tp[(e + 1) * LDIM];
        a2 += whs[e + 2] * tp[(e + 2) * LDIM];
        a3 += whs[e + 3] * tp[(e + 3) * LDIM];
    }
    const float z = (a0 + a1) + (a2 + a3);

    // block max
    float m = z;
    for (int off = 32; off > 0; off >>= 1)
        m = fmaxf(m, __shfl_down(m, off, 64));
    if ((tid & 63) == 0) redm[tid >> 6] = m;
    __syncthreads();
    m = fmaxf(fmaxf(fmaxf(redm[0], redm[1]), fmaxf(redm[2], redm[3])),
              fmaxf(redm[4], redm[5]));

    const float ez = expf(z - m);

    // block sum
    float s = ez;
    for (int off = 32; off > 0; off >>= 1)
        s += __shfl_down(s, off, 64);
    if ((tid & 63) == 0) reds[tid >> 6] = s;
    __syncthreads();
    const float rs = 1.f / (((reds[0] + reds[1]) + (reds[2] + reds[3]))
                            + (reds[4] + reds[5]));

    alpha[r * LDIM + tid] = ez * rs;
}

// ---------------------------------------------------------------------------
// Kernel 3: out[i][j][k] = v[j][k] * alpha[i][j]   (226.5 MB f32 writes)
// Restructured to mimic the 6.4 TB/s fill kernel:
//  - PLAIN float4 stores (nontemporal dropped — fill proves plain stores
//    hit peak; nt bypasses L2 write combining)
//  - zero divisions in the hot loop: 384 threads = exactly 4 v-rows per
//    iteration, so j = j0 + it*4 + (tid/96) with tid/96, tid%96 hoisted
//  - 4 blocks per i-slice, 384 threads -> 5 blocks/CU * 6 waves = 30/32 occ
// ---------------------------------------------------------------------------
__global__ __launch_bounds__(384) void k_out(
    const float* __restrict__ v, const float* __restrict__ alpha,
    float* __restrict__ out)
{
    constexpr int VPS = (LDIM * DDIM) / 4;   // 36864 vec4 per i-slice
    const int i = blockIdx.x >> 2;           // i-slice
    const int q = blockIdx.x & 3;            // quarter of the slice

    __shared__ float arow[DDIM];
    arow[threadIdx.x] = alpha[i * DDIM + threadIdx.x];  // 384 threads, 1:1
    __syncthreads();

    const int jb  = (int)threadIdx.x / 96;   // 0..3 (hoisted, once)
    const int col = (int)threadIdx.x % 96;   // vec4 column within row
    const int j0  = q * 96;                  // first j-row of this block

    const float4v* v4 = (const float4v*)v;
    float4v* o4 = (float4v*)out + (size_t)i * VPS;

    #pragma unroll 6
    for (int it = 0; it < 24; ++it) {        // 24 iters * 4 rows = 96 rows
        const int j   = j0 + it * 4 + jb;
        const int idx = j * 96 + col;        // contiguous across the block
        o4[idx] = v4[idx] * arow[j];
    }
}

// ---------------------------------------------------------------------------
extern "C" void kernel_launch(void* const* d_in, const int* in_sizes, int n_in,
                              void* d_out, int out_size, void* d_ws, size_t ws_size,
                              hipStream_t stream)
{
    const float* h  = (const float*)d_in[0];   // (512, 1)   f32
    const float* v  = (const float*)d_in[1];   // (384, 384) f32
    const float* wh = (const float*)d_in[2];   // (384, 512) f32
    const float* wv = (const float*)d_in[3];   // (512, 384) f32
    const float* wg = (const float*)d_in[4];   // (512, 512) f32
    float* out = (float*)d_out;                // (384, 384, 384) f32

    float* t     = (float*)d_ws;               // (512, 384) f32 scratch
    float* alpha = t + EDIM * LDIM;            // (384, 384) f32 scratch

    k_tanh_s <<<EDIM, 384, 0, stream>>>(h, v, wv, wg, t);
    k_softmax<<<LDIM, 384, 0, stream>>>(wh, t, alpha);
    k_out    <<<4 * LDIM, 384, 0, stream>>>(v, alpha, out);
}